// Round 5
// baseline (530.944 us; speedup 1.0000x reference)
//
#include <hip/hip_runtime.h>
#include <hip/hip_bf16.h>

// ---------------- sizes ----------------
#define BATCH 128
#define IMG   28
#define NCAP  1152          // 32*36
#define KDIM  20736         // 256*81
#define HLO_DELTA 13107200  // h_hi -> h_lo element delta (shorts)
#define WLO_DELTA 5308416   // wt_hi -> wt_lo element delta (shorts)

// ws offsets in floats
#define WT_OFF   ((size_t)0)            // wt hi+lo bf16 = 5308416 floats
#define U_OFF    ((size_t)0)            // alias wt (dead after conv2m)
#define H_OFF    ((size_t)5308416)      // h hi+lo bf16 = 13107200 floats
#define UH_OFF   (H_OFF)                // alias h (dead after conv2m): uh bf16 = 11796480 floats
#define FS_OFF   (H_OFF + (size_t)11796480)
#define IDX_OFF  (FS_OFF + (size_t)2048)
#define H1_OFF   (IDX_OFF + (size_t)128)
#define H2_OFF   (H1_OFF + (size_t)65536)
#define W1T_OFF  ((size_t)18415616)     // 20736 floats
#define PACC_OFF ((size_t)18436352)     // nz*4608*256 floats

using short8v = __attribute__((ext_vector_type(8))) short;
using f32x4   = __attribute__((ext_vector_type(4))) float;

__device__ inline void split2(float x, __hip_bfloat16& hi, __hip_bfloat16& lo)
{
    hi = __float2bfloat16(x);
    lo = __float2bfloat16(x - __bfloat162float(hi));
}
__device__ inline float bf16s2f(short s)
{
    return __uint_as_float(((unsigned)(unsigned short)s) << 16);
}

// ---------------- Wp (256,256,9,9) -> Wt [co][t][ci] bf16 hi/lo ----------------
__global__ __launch_bounds__(256) void k_wt(const float* __restrict__ wp, __hip_bfloat16* __restrict__ wt)
{
    __shared__ float lds[64 * 82];
    const int co = blockIdx.x;
    const int tid = threadIdx.x;
    for (int ci0 = 0; ci0 < 256; ci0 += 64) {
        for (int idx = tid; idx < 64 * 81; idx += 256) {
            const int cil = idx / 81, t = idx - cil * 81;
            lds[cil * 82 + t] = wp[(size_t)co * KDIM + (size_t)(ci0 + cil) * 81 + t];
        }
        __syncthreads();
        for (int idx = tid; idx < 81 * 64; idx += 256) {
            const int t = idx >> 6, cil = idx & 63;
            __hip_bfloat16 hi, lo;
            split2(lds[cil * 82 + t], hi, lo);
            const size_t o = (size_t)co * KDIM + (size_t)t * 256 + ci0 + cil;
            wt[o] = hi;
            wt[o + WLO_DELTA] = lo;
        }
        __syncthreads();
    }
}

// ---------------- W1 (256,81) -> w1t (81,256) ----------------
__global__ __launch_bounds__(256) void k_w1t(const float* __restrict__ w1, float* __restrict__ w1t)
{
    __shared__ float lds[16 * 81];
    const int r0 = blockIdx.x * 16;
    const int tid = threadIdx.x;
    for (int idx = tid; idx < 16 * 81; idx += 256)
        lds[idx] = w1[(size_t)(r0 + idx / 81) * 81 + (idx % 81)];
    __syncthreads();
    for (int idx = tid; idx < 81 * 16; idx += 256) {
        const int i = idx >> 4, rl = idx & 15;
        w1t[(size_t)i * 256 + r0 + rl] = lds[rl * 81 + i];
    }
}

// ---------------- conv1: 28x28x1 -> 20x20x256 (NHWC, bf16 hi/lo), relu ----------------
__global__ __launch_bounds__(256) void k_conv1(const float* __restrict__ img,
                                               const float* __restrict__ w1t,
                                               const float* __restrict__ b1,
                                               __hip_bfloat16* __restrict__ h)
{
    __shared__ float simg[IMG * IMG];
    const int b = blockIdx.x;
    const int y0 = blockIdx.y * 5;
    const int tid = threadIdx.x;
    for (int i = tid; i < IMG * IMG; i += 256) simg[i] = img[(size_t)b * IMG * IMG + i];
    float w[81];
#pragma unroll
    for (int i = 0; i < 81; ++i) w[i] = w1t[(size_t)i * 256 + tid];
    const float bias = b1[tid];
    __syncthreads();
    for (int y = y0; y < y0 + 5; ++y) {
        for (int xg = 0; xg < 5; ++xg) {
            float a0 = 0.f, a1 = 0.f, a2 = 0.f, a3 = 0.f;
#pragma unroll
            for (int ky = 0; ky < 9; ++ky) {
                float rb[12];
#pragma unroll
                for (int t = 0; t < 12; ++t) rb[t] = simg[(y + ky) * IMG + xg * 4 + t];
#pragma unroll
                for (int kx = 0; kx < 9; ++kx) {
                    const float wv = w[ky * 9 + kx];
                    a0 += wv * rb[kx + 0];
                    a1 += wv * rb[kx + 1];
                    a2 += wv * rb[kx + 2];
                    a3 += wv * rb[kx + 3];
                }
            }
            const size_t ob = (((size_t)b * 20 + y) * 20 + xg * 4) * 256 + tid;
            float av[4] = {a0, a1, a2, a3};
#pragma unroll
            for (int q = 0; q < 4; ++q) {
                __hip_bfloat16 hi, lo;
                split2(fmaxf(av[q] + bias, 0.f), hi, lo);
                h[ob + q * 256] = hi;
                h[ob + q * 256 + HLO_DELTA] = lo;
            }
        }
    }
}

// ---------------- conv2 split-bf16 MFMA implicit GEMM v3 ----------------
// Block 128(M)x256(N), 4 waves each 64x128. BK=32. LDS rows = 128B
// ([32sh hi | 32sh lo]) with T2 XOR swizzle byte^=((row&7)<<4) on both sides.
__global__ __launch_bounds__(256, 2) void k_conv2m(const __hip_bfloat16* __restrict__ hH,
                                                   const __hip_bfloat16* __restrict__ wH,
                                                   float* __restrict__ pacc,
                                                   int kslice, int ksteps)
{
    __shared__ short Alds[128 * 64];
    __shared__ short Blds[256 * 64];
    const int mt = blockIdx.x, z = blockIdx.y;
    const int tid = threadIdx.x;
    const int lane = tid & 63, wid = tid >> 6;
    const int wm = wid >> 1, wn = wid & 1;
    const int lr = lane & 15, kg = lane >> 4;
    const int k0base = z * kslice;

    // staging: 12 x b128 per thread (A: 4 rows, B: 8 rows; sub 0-3 = hi segs, 4-7 = lo segs)
    const int arow = tid >> 3, asub = tid & 7;
    const int aseg = asub & 3;
    const unsigned lodelA = (asub >= 4) ? (unsigned)HLO_DELTA : 0u;
    const unsigned lodelB = (asub >= 4) ? (unsigned)WLO_DELTA : 0u;

    unsigned aoffA[4];
#pragma unroll
    for (int i = 0; i < 4; ++i) {
        const int row = arow + 32 * i;
        const int m = mt * 128 + row;
        const int bb = m / 36, s = m - bb * 36;
        const int sy = s / 6, sx = s - sy * 6;
        aoffA[i] = (unsigned)((((bb * 20 + 2 * sy) * 20 + 2 * sx) * 256) + aseg * 8) + lodelA;
    }
    unsigned boffB[8];
#pragma unroll
    for (int i = 0; i < 8; ++i)
        boffB[i] = (unsigned)((arow + 32 * i) * KDIM + aseg * 8) + lodelB;
    int awr[4], bwr[8];
#pragma unroll
    for (int i = 0; i < 4; ++i) {
        const int row = arow + 32 * i;
        awr[i] = row * 64 + ((asub * 8) ^ ((row & 7) * 8));
    }
#pragma unroll
    for (int i = 0; i < 8; ++i) {
        const int row = arow + 32 * i;
        bwr[i] = row * 64 + ((asub * 8) ^ ((row & 7) * 8));
    }

    // fragment read offsets (swizzled)
    int ardH[4], ardL[4];
#pragma unroll
    for (int f = 0; f < 4; ++f) {
        const int row = wm * 64 + f * 16 + lr;
        const int sw = (row & 7) * 8;
        ardH[f] = row * 64 + ((kg * 8) ^ sw);
        ardL[f] = row * 64 + (((32 + kg * 8)) ^ sw);
    }
    int brdH[8], brdL[8];
#pragma unroll
    for (int f = 0; f < 8; ++f) {
        const int row = wn * 128 + f * 16 + lr;
        const int sw = (row & 7) * 8;
        brdH[f] = row * 64 + ((kg * 8) ^ sw);
        brdL[f] = row * 64 + (((32 + kg * 8)) ^ sw);
    }

    f32x4 acc[4][8];
#pragma unroll
    for (int i = 0; i < 4; ++i)
#pragma unroll
        for (int j = 0; j < 8; ++j)
            acc[i][j] = (f32x4){0.f, 0.f, 0.f, 0.f};

    short8v ra[4], rb[8];
    auto do_load = [&](int s) {
        const int k0 = k0base + s * 32;
        const int t = k0 >> 8, ci0 = k0 & 255;
        const int ky = t / 9, kx = t - ky * 9;
        const unsigned aoff = (unsigned)((ky * 20 + kx) * 256 + ci0);
#pragma unroll
        for (int i = 0; i < 4; ++i) ra[i] = *(const short8v*)(hH + aoffA[i] + aoff);
#pragma unroll
        for (int i = 0; i < 8; ++i) rb[i] = *(const short8v*)(wH + boffB[i] + (unsigned)k0);
    };

    do_load(0);
    for (int s = 0; s < ksteps; ++s) {
        __syncthreads();
#pragma unroll
        for (int i = 0; i < 4; ++i) *(short8v*)&Alds[awr[i]] = ra[i];
#pragma unroll
        for (int i = 0; i < 8; ++i) *(short8v*)&Blds[bwr[i]] = rb[i];
        __syncthreads();
        if (s + 1 < ksteps) do_load(s + 1);   // issue early, hides under MFMA
        short8v ah[4], al[4];
#pragma unroll
        for (int f = 0; f < 4; ++f) {
            ah[f] = *(const short8v*)&Alds[ardH[f]];
            al[f] = *(const short8v*)&Alds[ardL[f]];
        }
#pragma unroll
        for (int nf = 0; nf < 8; ++nf) {
            const short8v bh = *(const short8v*)&Blds[brdH[nf]];
            const short8v bl = *(const short8v*)&Blds[brdL[nf]];
#pragma unroll
            for (int f = 0; f < 4; ++f) {
                f32x4 a = acc[f][nf];
                a = __builtin_amdgcn_mfma_f32_16x16x32_bf16(al[f], bh, a, 0, 0, 0);
                a = __builtin_amdgcn_mfma_f32_16x16x32_bf16(ah[f], bl, a, 0, 0, 0);
                a = __builtin_amdgcn_mfma_f32_16x16x32_bf16(ah[f], bh, a, 0, 0, 0);
                acc[f][nf] = a;
            }
        }
    }

    float* po = pacc + (size_t)z * 4608 * 256;
    const int r4 = (lane >> 4) * 4, cc = lane & 15;
#pragma unroll
    for (int f = 0; f < 4; ++f) {
        const int row = mt * 128 + wm * 64 + f * 16 + r4;
#pragma unroll
        for (int nf = 0; nf < 8; ++nf) {
            const int col = wn * 128 + nf * 16 + cc;
#pragma unroll
            for (int j = 0; j < 4; ++j)
                po[(size_t)(row + j) * 256 + col] = acc[f][nf][j];
        }
    }
}

// ---------------- reduce split-K partials + bias + squash -> u layout ----------------
__global__ __launch_bounds__(256) void k_cred(const float* __restrict__ pacc,
                                              const float* __restrict__ bp,
                                              float* __restrict__ u, int nz)
{
    __shared__ float sv[256];
    const int m = blockIdx.x;
    const int co = threadIdx.x;
    float v = bp[co];
    for (int z = 0; z < nz; ++z) v += pacc[((size_t)z * 4608 + m) * 256 + co];
    sv[co] = v;
    __syncthreads();
    const int g = co & 31, d = co >> 5;
    float sq = 0.f;
#pragma unroll
    for (int dd = 0; dd < 8; ++dd) {
        const float t = sv[dd * 32 + g];
        sq += t * t;
    }
    const float sc = sqrtf(sq) / (1.f + sq);
    const int bo = m / 36, so = m - bo * 36;
    u[((size_t)bo * NCAP + g * 36 + so) * 8 + d] = v * sc;
}

// ---------------- u_hat GEMM: uh[c][b][n][e] (bf16) ----------------
__global__ __launch_bounds__(256) void k_uhat(const float* __restrict__ u,
                                              const float* __restrict__ wdig,
                                              __hip_bfloat16* __restrict__ uh)
{
    __shared__ float wlds[16384];   // 128 n x 128 (d*16+e)
    __shared__ float ulds[1024];    // 128 n x 8 d
    const int nc = blockIdx.x, c = blockIdx.y;
    const int n0 = nc * 128;
    const int tid = threadIdx.x;
    const float* wsrc = wdig + ((size_t)c * NCAP + n0) * 128;
    for (int i = tid * 4; i < 16384; i += 1024)
        *(float4*)&wlds[i] = *(const float4*)&wsrc[i];
    const int e = tid & 15, ng = tid >> 4;
    for (int b = 0; b < 128; ++b) {
        *(float4*)&ulds[tid * 4] = *(const float4*)(u + ((size_t)b * NCAP + n0) * 8 + tid * 4);
        __syncthreads();
        __hip_bfloat16 outv[8];
#pragma unroll
        for (int p = 0; p < 8; ++p) {
            const int nl = ng + p * 16;
            float a = 0.f;
#pragma unroll
            for (int d = 0; d < 8; ++d)
                a += ulds[nl * 8 + d] * wlds[nl * 128 + d * 16 + e];
            outv[p] = __float2bfloat16(a);
        }
        __hip_bfloat16* dst = uh + (((size_t)c * 128 + b) * NCAP + n0) * 16 + e;
#pragma unroll
        for (int p = 0; p < 8; ++p)
            dst[(size_t)(ng + p * 16) * 16] = outv[p];
        __syncthreads();
    }
}

// ---------------- 3-iter routing per (c,b), uh staged from global ----------------
__global__ __launch_bounds__(256) void k_routing(const __hip_bfloat16* __restrict__ uhg,
                                                 float* __restrict__ caps)
{
    __shared__ __hip_bfloat16 uh[NCAP * 16];
    __shared__ float bl[NCAP];
    __shared__ float wl[NCAP];
    __shared__ float red[256];
    __shared__ float sv[16], vv[16];
    __shared__ float sfac;
    const int c = blockIdx.x, b = blockIdx.y;
    const int tid = threadIdx.x;
    const int e = tid & 15, ng = tid >> 4;
    {
        const short8v* src = (const short8v*)(uhg + ((size_t)c * 128 + b) * NCAP * 16);
        short8v* dstv = (short8v*)uh;
        for (int i = tid; i < NCAP * 16 / 8; i += 256) dstv[i] = src[i];
    }
    for (int n = tid; n < NCAP; n += 256) bl[n] = 0.f;
    __syncthreads();
    for (int it = 0; it < 3; ++it) {
        float lm = -1e30f;
        for (int n = tid; n < NCAP; n += 256) lm = fmaxf(lm, bl[n]);
        red[tid] = lm; __syncthreads();
        for (int o = 128; o > 0; o >>= 1) { if (tid < o) red[tid] = fmaxf(red[tid], red[tid + o]); __syncthreads(); }
        const float mx = red[0]; __syncthreads();
        float lz = 0.f;
        for (int n = tid; n < NCAP; n += 256) { const float ev = __expf(bl[n] - mx); wl[n] = ev; lz += ev; }
        red[tid] = lz; __syncthreads();
        for (int o = 128; o > 0; o >>= 1) { if (tid < o) red[tid] += red[tid + o]; __syncthreads(); }
        const float Z = red[0]; __syncthreads();
        float ps = 0.f;
        for (int i = 0; i < 72; ++i) {
            const int n = ng + (i << 4);
            ps += wl[n] * __bfloat162float(uh[n * 16 + e]);
        }
        red[tid] = ps; __syncthreads();
        if (tid < 16) {
            float ss = 0.f;
#pragma unroll
            for (int g = 0; g < 16; ++g) ss += red[(g << 4) + tid];
            sv[tid] = ss / Z;
        }
        __syncthreads();
        if (tid == 0) {
            float sq = 0.f;
#pragma unroll
            for (int q = 0; q < 16; ++q) sq += sv[q] * sv[q];
            sfac = sqrtf(sq) / (1.f + sq);
        }
        __syncthreads();
        if (tid < 16) vv[tid] = sv[tid] * sfac;
        __syncthreads();
        if (it < 2) {
            for (int n = tid; n < NCAP; n += 256) {
                const short8v p0 = *(const short8v*)&uh[n * 16];
                const short8v p1 = *(const short8v*)&uh[n * 16 + 8];
                float dot = 0.f;
#pragma unroll
                for (int q = 0; q < 8; ++q) dot += bf16s2f(p0[q]) * vv[q] + bf16s2f(p1[q]) * vv[q + 8];
                bl[n] += dot;
            }
            __syncthreads();
        }
    }
    if (tid < 16) caps[((size_t)b * 10 + c) * 16 + tid] = vv[tid];
}

// ---------------- argmax-mask / one-hot ----------------
__global__ __launch_bounds__(64) void k_sel(const float* __restrict__ caps,
                                            float* __restrict__ yout,
                                            float* __restrict__ fs,
                                            float* __restrict__ idxf)
{
    __shared__ float nrm[10];
    __shared__ int bi;
    const int b = blockIdx.x, t = threadIdx.x;
    if (t < 10) {
        const float* cp = caps + ((size_t)b * 10 + t) * 16;
        float s = 0.f;
#pragma unroll
        for (int q = 0; q < 16; ++q) s += cp[q] * cp[q];
        nrm[t] = s;
    }
    __syncthreads();
    if (t == 0) {
        int best = 0; float bv = nrm[0];
        for (int q = 1; q < 10; ++q) if (nrm[q] > bv) { bv = nrm[q]; best = q; }
        bi = best; idxf[b] = (float)best;
    }
    __syncthreads();
    if (t < 10) yout[b * 10 + t] = (t == bi) ? 1.f : 0.f;
    if (t < 16) fs[b * 16 + t] = caps[((size_t)b * 10 + bi) * 16 + t];
}

// ---------------- decoder fc1 ----------------
__global__ __launch_bounds__(512) void k_fc1(const float* __restrict__ fs,
                                             const float* __restrict__ idxf,
                                             const float* __restrict__ Wd1,
                                             const float* __restrict__ bd1,
                                             float* __restrict__ h1)
{
    __shared__ float f[16];
    __shared__ int ib;
    const int b = blockIdx.x, j = threadIdx.x;
    if (j == 0) ib = (int)idxf[b];
    if (j < 16) f[j] = fs[b * 16 + j];
    __syncthreads();
    float a = bd1[j];
    const float* w = Wd1 + (size_t)(ib * 16) * 512 + j;
#pragma unroll
    for (int q = 0; q < 16; ++q) a += f[q] * w[q * 512];
    h1[(size_t)b * 512 + j] = fmaxf(a, 0.f);
}

// ---------------- decoder fc2: 512 -> 1024, relu ----------------
__global__ __launch_bounds__(256) void k_fc2(const float* __restrict__ h1,
                                             const float* __restrict__ Wd2,
                                             const float* __restrict__ bd2,
                                             float* __restrict__ h2)
{
    __shared__ float lh[16 * 512];
    const int jt = blockIdx.x, bt = blockIdx.y * 16;
    const int tid = threadIdx.x;
    for (int idx = tid; idx < 16 * 512; idx += 256)
        lh[idx] = h1[(size_t)(bt + (idx >> 9)) * 512 + (idx & 511)];
    __syncthreads();
    const int j = jt * 256 + tid;
    float acc[16];
#pragma unroll
    for (int q = 0; q < 16; ++q) acc[q] = 0.f;
    for (int k = 0; k < 512; k += 4) {
        const float w0 = Wd2[(size_t)(k + 0) * 1024 + j];
        const float w1 = Wd2[(size_t)(k + 1) * 1024 + j];
        const float w2 = Wd2[(size_t)(k + 2) * 1024 + j];
        const float w3 = Wd2[(size_t)(k + 3) * 1024 + j];
#pragma unroll
        for (int q = 0; q < 16; ++q) {
            const float4 lv = *(const float4*)&lh[q * 512 + k];
            acc[q] += lv.x * w0 + lv.y * w1 + lv.z * w2 + lv.w * w3;
        }
    }
    const float bias = bd2[j];
#pragma unroll
    for (int q = 0; q < 16; ++q)
        h2[(size_t)(bt + q) * 1024 + j] = fmaxf(acc[q] + bias, 0.f);
}

// ---------------- decoder fc3: 1024 -> 784, sigmoid ----------------
__global__ __launch_bounds__(256) void k_fc3(const float* __restrict__ h2,
                                             const float* __restrict__ Wd3,
                                             const float* __restrict__ bd3,
                                             float* __restrict__ rec)
{
    __shared__ float lh[8 * 1024];
    const int jt = blockIdx.x, bt = blockIdx.y * 8;
    const int tid = threadIdx.x;
    for (int idx = tid; idx < 8 * 1024; idx += 256)
        lh[idx] = h2[(size_t)(bt + (idx >> 10)) * 1024 + (idx & 1023)];
    __syncthreads();
    const int j = jt * 256 + tid;
    if (j < 784) {
        float acc[8];
#pragma unroll
        for (int q = 0; q < 8; ++q) acc[q] = 0.f;
        for (int k = 0; k < 1024; k += 4) {
            const float w0 = Wd3[(size_t)(k + 0) * 784 + j];
            const float w1 = Wd3[(size_t)(k + 1) * 784 + j];
            const float w2 = Wd3[(size_t)(k + 2) * 784 + j];
            const float w3 = Wd3[(size_t)(k + 3) * 784 + j];
#pragma unroll
            for (int q = 0; q < 8; ++q) {
                const float4 lv = *(const float4*)&lh[q * 1024 + k];
                acc[q] += lv.x * w0 + lv.y * w1 + lv.z * w2 + lv.w * w3;
            }
        }
        const float bias = bd3[j];
#pragma unroll
        for (int q = 0; q < 8; ++q) {
            const float x = acc[q] + bias;
            rec[(size_t)(bt + q) * 784 + j] = 1.f / (1.f + __expf(-x));
        }
    }
}

extern "C" void kernel_launch(void* const* d_in, const int* in_sizes, int n_in,
                              void* d_out, int out_size, void* d_ws, size_t ws_size,
                              hipStream_t stream)
{
    const float* images = (const float*)d_in[0];
    const float* W1   = (const float*)d_in[1];
    const float* b1   = (const float*)d_in[2];
    const float* Wp   = (const float*)d_in[3];
    const float* bp   = (const float*)d_in[4];
    const float* Wdig = (const float*)d_in[5];
    const float* Wd1  = (const float*)d_in[6];
    const float* bd1  = (const float*)d_in[7];
    const float* Wd2  = (const float*)d_in[8];
    const float* bd2  = (const float*)d_in[9];
    const float* Wd3  = (const float*)d_in[10];
    const float* bd3  = (const float*)d_in[11];
    float* ws  = (float*)d_ws;
    float* out = (float*)d_out;
    __hip_bfloat16* wt = (__hip_bfloat16*)(ws + WT_OFF);   // hi then lo
    __hip_bfloat16* h  = (__hip_bfloat16*)(ws + H_OFF);    // hi then lo
    __hip_bfloat16* uh = (__hip_bfloat16*)(ws + UH_OFF);   // aliases h (dead after conv2m)
    float* u    = ws + U_OFF;     // aliases wt (dead after conv2m)
    float* fs   = ws + FS_OFF;
    float* idxf = ws + IDX_OFF;
    float* h1   = ws + H1_OFF;
    float* h2   = ws + H2_OFF;
    float* w1t  = ws + W1T_OFF;
    float* pacc = ws + PACC_OFF;
    float* caps = out;                       // 128*10*16
    float* rec  = out + 20480;               // 128*784
    float* yout = out + 20480 + 100352;      // 128*10

    // split-K factor, scratch-size gated (all divide 648 K-steps evenly)
    int nz = 4;
    if (ws_size >= (PACC_OFF + (size_t)12 * 1179648) * 4) nz = 12;
    else if (ws_size >= (PACC_OFF + (size_t)9 * 1179648) * 4) nz = 9;
    const int kslice = KDIM / nz;
    const int ksteps = kslice / 32;

    k_wt    <<<256, 256, 0, stream>>>(Wp, wt);
    k_w1t   <<<16, 256, 0, stream>>>(W1, w1t);
    k_conv1 <<<dim3(128, 4), 256, 0, stream>>>(images, w1t, b1, h);
    k_conv2m<<<dim3(36, nz), 256, 0, stream>>>(h, wt, pacc, kslice, ksteps);
    k_cred  <<<4608, 256, 0, stream>>>(pacc, bp, u, nz);
    k_uhat  <<<dim3(9, 10), 256, 0, stream>>>(u, Wdig, uh);
    k_routing<<<dim3(10, 128), 256, 0, stream>>>(uh, caps);
    k_sel   <<<128, 64, 0, stream>>>(caps, yout, fs, idxf);
    k_fc1   <<<128, 512, 0, stream>>>(fs, idxf, Wd1, bd1, h1);
    k_fc2   <<<dim3(4, 8), 256, 0, stream>>>(h1, Wd2, bd2, h2);
    k_fc3   <<<dim3(4, 16), 256, 0, stream>>>(h2, Wd3, bd3, rec);
}

// Round 6
// 402.927 us; speedup vs baseline: 1.3177x; 1.3177x over previous
//
#include <hip/hip_runtime.h>
#include <hip/hip_bf16.h>

// ---------------- sizes ----------------
#define BATCH 128
#define IMG   28
#define NCAP  1152          // 32*36
#define KDIM  20736         // 256*81
#define HLO_DELTA 13107200  // h_hi -> h_lo element delta (shorts)
#define WLO_DELTA 5308416   // wt_hi -> wt_lo element delta (shorts)

// ws offsets in floats
#define WT_OFF   ((size_t)0)            // wt hi+lo bf16 = 5308416 floats
#define U_OFF    ((size_t)0)            // alias wt (dead after conv2m)
#define H_OFF    ((size_t)5308416)      // h hi+lo bf16 = 13107200 floats
#define UH_OFF   (H_OFF)                // alias h (dead after conv2m): uh bf16 = 11796480 floats
#define FS_OFF   (H_OFF + (size_t)11796480)
#define IDX_OFF  (FS_OFF + (size_t)2048)
#define H1_OFF   (IDX_OFF + (size_t)128)
#define H2_OFF   (H1_OFF + (size_t)65536)
#define W1T_OFF  ((size_t)18415616)     // 20736 floats
#define PACC_OFF ((size_t)18436352)     // nz*4608*256 floats

using short8v = __attribute__((ext_vector_type(8))) short;
using f32x4   = __attribute__((ext_vector_type(4))) float;

__device__ inline void split2(float x, __hip_bfloat16& hi, __hip_bfloat16& lo)
{
    hi = __float2bfloat16(x);
    lo = __float2bfloat16(x - __bfloat162float(hi));
}
__device__ inline float bf16s2f(short s)
{
    return __uint_as_float(((unsigned)(unsigned short)s) << 16);
}

// ---------------- Wp (256,256,9,9) -> Wt [co][t][ci] bf16 hi/lo ----------------
__global__ __launch_bounds__(256) void k_wt(const float* __restrict__ wp, __hip_bfloat16* __restrict__ wt)
{
    __shared__ float lds[64 * 82];
    const int co = blockIdx.x;
    const int tid = threadIdx.x;
    for (int ci0 = 0; ci0 < 256; ci0 += 64) {
        for (int idx = tid; idx < 64 * 81; idx += 256) {
            const int cil = idx / 81, t = idx - cil * 81;
            lds[cil * 82 + t] = wp[(size_t)co * KDIM + (size_t)(ci0 + cil) * 81 + t];
        }
        __syncthreads();
        for (int idx = tid; idx < 81 * 64; idx += 256) {
            const int t = idx >> 6, cil = idx & 63;
            __hip_bfloat16 hi, lo;
            split2(lds[cil * 82 + t], hi, lo);
            const size_t o = (size_t)co * KDIM + (size_t)t * 256 + ci0 + cil;
            wt[o] = hi;
            wt[o + WLO_DELTA] = lo;
        }
        __syncthreads();
    }
}

// ---------------- W1 (256,81) -> w1t (81,256) ----------------
__global__ __launch_bounds__(256) void k_w1t(const float* __restrict__ w1, float* __restrict__ w1t)
{
    __shared__ float lds[16 * 81];
    const int r0 = blockIdx.x * 16;
    const int tid = threadIdx.x;
    for (int idx = tid; idx < 16 * 81; idx += 256)
        lds[idx] = w1[(size_t)(r0 + idx / 81) * 81 + (idx % 81)];
    __syncthreads();
    for (int idx = tid; idx < 81 * 16; idx += 256) {
        const int i = idx >> 4, rl = idx & 15;
        w1t[(size_t)i * 256 + r0 + rl] = lds[rl * 81 + i];
    }
}

// ---------------- conv1: 28x28x1 -> 20x20x256 (NHWC, bf16 hi/lo), relu ----------------
__global__ __launch_bounds__(256) void k_conv1(const float* __restrict__ img,
                                               const float* __restrict__ w1t,
                                               const float* __restrict__ b1,
                                               __hip_bfloat16* __restrict__ h)
{
    __shared__ float simg[IMG * IMG];
    const int b = blockIdx.x;
    const int y0 = blockIdx.y * 5;
    const int tid = threadIdx.x;
    for (int i = tid; i < IMG * IMG; i += 256) simg[i] = img[(size_t)b * IMG * IMG + i];
    float w[81];
#pragma unroll
    for (int i = 0; i < 81; ++i) w[i] = w1t[(size_t)i * 256 + tid];
    const float bias = b1[tid];
    __syncthreads();
    for (int y = y0; y < y0 + 5; ++y) {
        for (int xg = 0; xg < 5; ++xg) {
            float a0 = 0.f, a1 = 0.f, a2 = 0.f, a3 = 0.f;
#pragma unroll
            for (int ky = 0; ky < 9; ++ky) {
                float rb[12];
#pragma unroll
                for (int t = 0; t < 12; ++t) rb[t] = simg[(y + ky) * IMG + xg * 4 + t];
#pragma unroll
                for (int kx = 0; kx < 9; ++kx) {
                    const float wv = w[ky * 9 + kx];
                    a0 += wv * rb[kx + 0];
                    a1 += wv * rb[kx + 1];
                    a2 += wv * rb[kx + 2];
                    a3 += wv * rb[kx + 3];
                }
            }
            const size_t ob = (((size_t)b * 20 + y) * 20 + xg * 4) * 256 + tid;
            float av[4] = {a0, a1, a2, a3};
#pragma unroll
            for (int q = 0; q < 4; ++q) {
                __hip_bfloat16 hi, lo;
                split2(fmaxf(av[q] + bias, 0.f), hi, lo);
                h[ob + q * 256] = hi;
                h[ob + q * 256 + HLO_DELTA] = lo;
            }
        }
    }
}

// ---------------- conv2 split-bf16 MFMA implicit GEMM v4 ----------------
// Block 128(M)x256(N), 4 waves each 64x128, BK=32, T2-swizzled LDS (conflict-free).
// Split-K by (tap-group x ci-chunk): ci-disjoint slices kill A-refetch.
// 1D grid with bijective XCD swizzle: same-z blocks share an XCD (B-panel L2 reuse).
__global__ __launch_bounds__(256, 2) void k_conv2m(const __hip_bfloat16* __restrict__ hH,
                                                   const __hip_bfloat16* __restrict__ wH,
                                                   float* __restrict__ pacc,
                                                   int ksteps, int lgci, int ncg, int tpz)
{
    __shared__ short Alds[128 * 64];
    __shared__ short Blds[256 * 64];
    // bijective XCD swizzle (gridDim.x divisible by 8)
    const int q = gridDim.x >> 3;
    const int wg = blockIdx.x;
    const int wgid = (wg & 7) * q + (wg >> 3);
    const int z = wgid / 36;
    const int mt = wgid - z * 36;
    const int tg = z / ncg, cg = z - tg * ncg;
    const int tapbase = tg * tpz;
    const int cibase = cg * (32 << lgci);
    const int cimask = (1 << lgci) - 1;

    const int tid = threadIdx.x;
    const int lane = tid & 63, wid = tid >> 6;
    const int wm = wid >> 1, wn = wid & 1;
    const int lr = lane & 15, kg = lane >> 4;

    // staging: 12 x b128 per thread (A: 4 rows, B: 8 rows; sub 0-3 = hi segs, 4-7 = lo segs)
    const int arow = tid >> 3, asub = tid & 7;
    const int aseg = asub & 3;
    const unsigned lodelA = (asub >= 4) ? (unsigned)HLO_DELTA : 0u;
    const unsigned lodelB = (asub >= 4) ? (unsigned)WLO_DELTA : 0u;

    unsigned aoffA[4];
#pragma unroll
    for (int i = 0; i < 4; ++i) {
        const int row = arow + 32 * i;
        const int m = mt * 128 + row;
        const int bb = m / 36, s = m - bb * 36;
        const int sy = s / 6, sx = s - sy * 6;
        aoffA[i] = (unsigned)((((bb * 20 + 2 * sy) * 20 + 2 * sx) * 256) + aseg * 8) + lodelA;
    }
    unsigned boffB[8];
#pragma unroll
    for (int i = 0; i < 8; ++i)
        boffB[i] = (unsigned)((arow + 32 * i) * KDIM + aseg * 8) + lodelB;
    int awr[4], bwr[8];
#pragma unroll
    for (int i = 0; i < 4; ++i) {
        const int row = arow + 32 * i;
        awr[i] = row * 64 + ((asub * 8) ^ ((row & 7) * 8));
    }
#pragma unroll
    for (int i = 0; i < 8; ++i) {
        const int row = arow + 32 * i;
        bwr[i] = row * 64 + ((asub * 8) ^ ((row & 7) * 8));
    }

    // fragment read offsets (swizzled)
    int ardH[4], ardL[4];
#pragma unroll
    for (int f = 0; f < 4; ++f) {
        const int row = wm * 64 + f * 16 + lr;
        const int sw = (row & 7) * 8;
        ardH[f] = row * 64 + ((kg * 8) ^ sw);
        ardL[f] = row * 64 + (((32 + kg * 8)) ^ sw);
    }
    int brdH[8], brdL[8];
#pragma unroll
    for (int f = 0; f < 8; ++f) {
        const int row = wn * 128 + f * 16 + lr;
        const int sw = (row & 7) * 8;
        brdH[f] = row * 64 + ((kg * 8) ^ sw);
        brdL[f] = row * 64 + (((32 + kg * 8)) ^ sw);
    }

    f32x4 acc[4][8];
#pragma unroll
    for (int i = 0; i < 4; ++i)
#pragma unroll
        for (int j = 0; j < 8; ++j)
            acc[i][j] = (f32x4){0.f, 0.f, 0.f, 0.f};

    short8v ra[4], rb[8];
    auto do_load = [&](int s) {
        const int tap = tapbase + (s >> lgci);
        const int ci0 = cibase + (s & cimask) * 32;
        const int ky = tap / 9, kx = tap - ky * 9;
        const unsigned aoff = (unsigned)((ky * 20 + kx) * 256 + ci0);
        const unsigned boff = (unsigned)(tap * 256 + ci0);
#pragma unroll
        for (int i = 0; i < 4; ++i) ra[i] = *(const short8v*)(hH + aoffA[i] + aoff);
#pragma unroll
        for (int i = 0; i < 8; ++i) rb[i] = *(const short8v*)(wH + boffB[i] + boff);
    };

    do_load(0);
    for (int s = 0; s < ksteps; ++s) {
        __syncthreads();
#pragma unroll
        for (int i = 0; i < 4; ++i) *(short8v*)&Alds[awr[i]] = ra[i];
#pragma unroll
        for (int i = 0; i < 8; ++i) *(short8v*)&Blds[bwr[i]] = rb[i];
        __syncthreads();
        if (s + 1 < ksteps) do_load(s + 1);   // issue early, hides under MFMA
        short8v ah[4], al[4];
#pragma unroll
        for (int f = 0; f < 4; ++f) {
            ah[f] = *(const short8v*)&Alds[ardH[f]];
            al[f] = *(const short8v*)&Alds[ardL[f]];
        }
#pragma unroll
        for (int nf = 0; nf < 8; ++nf) {
            const short8v bh = *(const short8v*)&Blds[brdH[nf]];
            const short8v bl = *(const short8v*)&Blds[brdL[nf]];
#pragma unroll
            for (int f = 0; f < 4; ++f) {
                f32x4 a = acc[f][nf];
                a = __builtin_amdgcn_mfma_f32_16x16x32_bf16(al[f], bh, a, 0, 0, 0);
                a = __builtin_amdgcn_mfma_f32_16x16x32_bf16(ah[f], bl, a, 0, 0, 0);
                a = __builtin_amdgcn_mfma_f32_16x16x32_bf16(ah[f], bh, a, 0, 0, 0);
                acc[f][nf] = a;
            }
        }
    }

    float* po = pacc + (size_t)z * 4608 * 256;
    const int r4 = (lane >> 4) * 4, cc = lane & 15;
#pragma unroll
    for (int f = 0; f < 4; ++f) {
        const int row = mt * 128 + wm * 64 + f * 16 + r4;
#pragma unroll
        for (int nf = 0; nf < 8; ++nf) {
            const int col = wn * 128 + nf * 16 + cc;
#pragma unroll
            for (int j = 0; j < 4; ++j)
                po[(size_t)(row + j) * 256 + col] = acc[f][nf][j];
        }
    }
}

// ---------------- reduce split-K partials + bias + squash -> u layout ----------------
__global__ __launch_bounds__(256) void k_cred(const float* __restrict__ pacc,
                                              const float* __restrict__ bp,
                                              float* __restrict__ u, int nz)
{
    __shared__ float sv[256];
    const int m = blockIdx.x;
    const int co = threadIdx.x;
    float v = bp[co];
    for (int z = 0; z < nz; ++z) v += pacc[((size_t)z * 4608 + m) * 256 + co];
    sv[co] = v;
    __syncthreads();
    const int g = co & 31, d = co >> 5;
    float sq = 0.f;
#pragma unroll
    for (int dd = 0; dd < 8; ++dd) {
        const float t = sv[dd * 32 + g];
        sq += t * t;
    }
    const float sc = sqrtf(sq) / (1.f + sq);
    const int bo = m / 36, so = m - bo * 36;
    u[((size_t)bo * NCAP + g * 36 + so) * 8 + d] = v * sc;
}

// ---------------- u_hat: uh[c][b][n][e] (bf16) -- W in regs, b-chunked ----------------
__global__ __launch_bounds__(256) void k_uhat(const float* __restrict__ u,
                                              const float* __restrict__ wdig,
                                              __hip_bfloat16* __restrict__ uh)
{
    __shared__ float ulds[8 * 16 * 8];  // 4 KB: [bl][nl][d]
    const int n0 = blockIdx.x * 16, c = blockIdx.y;
    const int tid = threadIdx.x;
    const int nl = tid >> 4, e = tid & 15;
    float wreg[8];
#pragma unroll
    for (int d = 0; d < 8; ++d)
        wreg[d] = wdig[(((size_t)c * NCAP + n0 + nl) * 8 + d) * 16 + e];
    const int sbl = tid >> 5, srem = tid & 31;
    const int snn = srem >> 1, shalf = (srem & 1) * 4;
    for (int bc = 0; bc < 16; ++bc) {
        const int b0 = bc * 8;
        *(float4*)&ulds[(sbl * 16 + snn) * 8 + shalf] =
            *(const float4*)&u[((size_t)(b0 + sbl) * NCAP + n0 + snn) * 8 + shalf];
        __syncthreads();
        __hip_bfloat16 ov[8];
#pragma unroll
        for (int bl = 0; bl < 8; ++bl) {
            float a = 0.f;
#pragma unroll
            for (int d = 0; d < 8; ++d) a += ulds[(bl * 16 + nl) * 8 + d] * wreg[d];
            ov[bl] = __float2bfloat16(a);
        }
#pragma unroll
        for (int bl = 0; bl < 8; ++bl)
            uh[(((size_t)c * 128 + b0 + bl) * NCAP + n0 + nl) * 16 + e] = ov[bl];
        __syncthreads();
    }
}

// ---------------- 3-iter routing per (c,b), uh staged from global ----------------
__global__ __launch_bounds__(256) void k_routing(const __hip_bfloat16* __restrict__ uhg,
                                                 float* __restrict__ caps)
{
    __shared__ __hip_bfloat16 uh[NCAP * 16];
    __shared__ float bl[NCAP];
    __shared__ float wl[NCAP];
    __shared__ float red[256];
    __shared__ float sv[16], vv[16];
    __shared__ float sfac;
    const int c = blockIdx.x, b = blockIdx.y;
    const int tid = threadIdx.x;
    const int e = tid & 15, ng = tid >> 4;
    {
        const short8v* src = (const short8v*)(uhg + ((size_t)c * 128 + b) * NCAP * 16);
        short8v* dstv = (short8v*)uh;
        for (int i = tid; i < NCAP * 16 / 8; i += 256) dstv[i] = src[i];
    }
    for (int n = tid; n < NCAP; n += 256) bl[n] = 0.f;
    __syncthreads();
    for (int it = 0; it < 3; ++it) {
        float lm = -1e30f;
        for (int n = tid; n < NCAP; n += 256) lm = fmaxf(lm, bl[n]);
        red[tid] = lm; __syncthreads();
        for (int o = 128; o > 0; o >>= 1) { if (tid < o) red[tid] = fmaxf(red[tid], red[tid + o]); __syncthreads(); }
        const float mx = red[0]; __syncthreads();
        float lz = 0.f;
        for (int n = tid; n < NCAP; n += 256) { const float ev = __expf(bl[n] - mx); wl[n] = ev; lz += ev; }
        red[tid] = lz; __syncthreads();
        for (int o = 128; o > 0; o >>= 1) { if (tid < o) red[tid] += red[tid + o]; __syncthreads(); }
        const float Z = red[0]; __syncthreads();
        float ps = 0.f;
        for (int i = 0; i < 72; ++i) {
            const int n = ng + (i << 4);
            ps += wl[n] * __bfloat162float(uh[n * 16 + e]);
        }
        red[tid] = ps; __syncthreads();
        if (tid < 16) {
            float ss = 0.f;
#pragma unroll
            for (int g = 0; g < 16; ++g) ss += red[(g << 4) + tid];
            sv[tid] = ss / Z;
        }
        __syncthreads();
        if (tid == 0) {
            float sq = 0.f;
#pragma unroll
            for (int q = 0; q < 16; ++q) sq += sv[q] * sv[q];
            sfac = sqrtf(sq) / (1.f + sq);
        }
        __syncthreads();
        if (tid < 16) vv[tid] = sv[tid] * sfac;
        __syncthreads();
        if (it < 2) {
            for (int n = tid; n < NCAP; n += 256) {
                const short8v p0 = *(const short8v*)&uh[n * 16];
                const short8v p1 = *(const short8v*)&uh[n * 16 + 8];
                float dot = 0.f;
#pragma unroll
                for (int q = 0; q < 8; ++q) dot += bf16s2f(p0[q]) * vv[q] + bf16s2f(p1[q]) * vv[q + 8];
                bl[n] += dot;
            }
            __syncthreads();
        }
    }
    if (tid < 16) caps[((size_t)b * 10 + c) * 16 + tid] = vv[tid];
}

// ---------------- argmax-mask / one-hot ----------------
__global__ __launch_bounds__(64) void k_sel(const float* __restrict__ caps,
                                            float* __restrict__ yout,
                                            float* __restrict__ fs,
                                            float* __restrict__ idxf)
{
    __shared__ float nrm[10];
    __shared__ int bi;
    const int b = blockIdx.x, t = threadIdx.x;
    if (t < 10) {
        const float* cp = caps + ((size_t)b * 10 + t) * 16;
        float s = 0.f;
#pragma unroll
        for (int q = 0; q < 16; ++q) s += cp[q] * cp[q];
        nrm[t] = s;
    }
    __syncthreads();
    if (t == 0) {
        int best = 0; float bv = nrm[0];
        for (int q = 1; q < 10; ++q) if (nrm[q] > bv) { bv = nrm[q]; best = q; }
        bi = best; idxf[b] = (float)best;
    }
    __syncthreads();
    if (t < 10) yout[b * 10 + t] = (t == bi) ? 1.f : 0.f;
    if (t < 16) fs[b * 16 + t] = caps[((size_t)b * 10 + bi) * 16 + t];
}

// ---------------- decoder fc1 ----------------
__global__ __launch_bounds__(512) void k_fc1(const float* __restrict__ fs,
                                             const float* __restrict__ idxf,
                                             const float* __restrict__ Wd1,
                                             const float* __restrict__ bd1,
                                             float* __restrict__ h1)
{
    __shared__ float f[16];
    __shared__ int ib;
    const int b = blockIdx.x, j = threadIdx.x;
    if (j == 0) ib = (int)idxf[b];
    if (j < 16) f[j] = fs[b * 16 + j];
    __syncthreads();
    float a = bd1[j];
    const float* w = Wd1 + (size_t)(ib * 16) * 512 + j;
#pragma unroll
    for (int q = 0; q < 16; ++q) a += f[q] * w[q * 512];
    h1[(size_t)b * 512 + j] = fmaxf(a, 0.f);
}

// ---------------- decoder fc2: 512 -> 1024, relu ----------------
__global__ __launch_bounds__(256) void k_fc2(const float* __restrict__ h1,
                                             const float* __restrict__ Wd2,
                                             const float* __restrict__ bd2,
                                             float* __restrict__ h2)
{
    __shared__ float lh[16 * 512];
    const int jt = blockIdx.x, bt = blockIdx.y * 16;
    const int tid = threadIdx.x;
    for (int idx = tid; idx < 16 * 512; idx += 256)
        lh[idx] = h1[(size_t)(bt + (idx >> 9)) * 512 + (idx & 511)];
    __syncthreads();
    const int j = jt * 256 + tid;
    float acc[16];
#pragma unroll
    for (int q = 0; q < 16; ++q) acc[q] = 0.f;
    for (int k = 0; k < 512; k += 4) {
        const float w0 = Wd2[(size_t)(k + 0) * 1024 + j];
        const float w1 = Wd2[(size_t)(k + 1) * 1024 + j];
        const float w2 = Wd2[(size_t)(k + 2) * 1024 + j];
        const float w3 = Wd2[(size_t)(k + 3) * 1024 + j];
#pragma unroll
        for (int q = 0; q < 16; ++q) {
            const float4 lv = *(const float4*)&lh[q * 512 + k];
            acc[q] += lv.x * w0 + lv.y * w1 + lv.z * w2 + lv.w * w3;
        }
    }
    const float bias = bd2[j];
#pragma unroll
    for (int q = 0; q < 16; ++q)
        h2[(size_t)(bt + q) * 1024 + j] = fmaxf(acc[q] + bias, 0.f);
}

// ---------------- decoder fc3: 1024 -> 784, sigmoid ----------------
__global__ __launch_bounds__(256) void k_fc3(const float* __restrict__ h2,
                                             const float* __restrict__ Wd3,
                                             const float* __restrict__ bd3,
                                             float* __restrict__ rec)
{
    __shared__ float lh[8 * 1024];
    const int jt = blockIdx.x, bt = blockIdx.y * 8;
    const int tid = threadIdx.x;
    for (int idx = tid; idx < 8 * 1024; idx += 256)
        lh[idx] = h2[(size_t)(bt + (idx >> 10)) * 1024 + (idx & 1023)];
    __syncthreads();
    const int j = jt * 256 + tid;
    if (j < 784) {
        float acc[8];
#pragma unroll
        for (int q = 0; q < 8; ++q) acc[q] = 0.f;
        for (int k = 0; k < 1024; k += 4) {
            const float w0 = Wd3[(size_t)(k + 0) * 784 + j];
            const float w1 = Wd3[(size_t)(k + 1) * 784 + j];
            const float w2 = Wd3[(size_t)(k + 2) * 784 + j];
            const float w3 = Wd3[(size_t)(k + 3) * 784 + j];
#pragma unroll
            for (int q = 0; q < 8; ++q) {
                const float4 lv = *(const float4*)&lh[q * 1024 + k];
                acc[q] += lv.x * w0 + lv.y * w1 + lv.z * w2 + lv.w * w3;
            }
        }
        const float bias = bd3[j];
#pragma unroll
        for (int q = 0; q < 8; ++q) {
            const float x = acc[q] + bias;
            rec[(size_t)(bt + q) * 784 + j] = 1.f / (1.f + __expf(-x));
        }
    }
}

extern "C" void kernel_launch(void* const* d_in, const int* in_sizes, int n_in,
                              void* d_out, int out_size, void* d_ws, size_t ws_size,
                              hipStream_t stream)
{
    const float* images = (const float*)d_in[0];
    const float* W1   = (const float*)d_in[1];
    const float* b1   = (const float*)d_in[2];
    const float* Wp   = (const float*)d_in[3];
    const float* bp   = (const float*)d_in[4];
    const float* Wdig = (const float*)d_in[5];
    const float* Wd1  = (const float*)d_in[6];
    const float* bd1  = (const float*)d_in[7];
    const float* Wd2  = (const float*)d_in[8];
    const float* bd2  = (const float*)d_in[9];
    const float* Wd3  = (const float*)d_in[10];
    const float* bd3  = (const float*)d_in[11];
    float* ws  = (float*)d_ws;
    float* out = (float*)d_out;
    __hip_bfloat16* wt = (__hip_bfloat16*)(ws + WT_OFF);   // hi then lo
    __hip_bfloat16* h  = (__hip_bfloat16*)(ws + H_OFF);    // hi then lo
    __hip_bfloat16* uh = (__hip_bfloat16*)(ws + UH_OFF);   // aliases h (dead after conv2m)
    float* u    = ws + U_OFF;     // aliases wt (dead after conv2m)
    float* fs   = ws + FS_OFF;
    float* idxf = ws + IDX_OFF;
    float* h1   = ws + H1_OFF;
    float* h2   = ws + H2_OFF;
    float* w1t  = ws + W1T_OFF;
    float* pacc = ws + PACC_OFF;
    float* caps = out;                       // 128*10*16
    float* rec  = out + 20480;               // 128*784
    float* yout = out + 20480 + 100352;      // 128*10

    // split-K: ci-disjoint slices (tap-group x ci-chunk). nz=12: 3 tap-groups(27) x 4 ci(64).
    // Fallback nz=4: 1 tap-group(81) x 4 ci(64). Both keep A-fetch ~= h size (no tap-only refetch).
    int nz, tpz, ncg = 4, lgci = 1;
    if (ws_size >= (PACC_OFF + (size_t)12 * 1179648) * 4) { nz = 12; tpz = 27; }
    else                                                  { nz = 4;  tpz = 81; }
    const int ksteps = (KDIM / nz) / 32;

    k_wt    <<<256, 256, 0, stream>>>(Wp, wt);
    k_w1t   <<<16, 256, 0, stream>>>(W1, w1t);
    k_conv1 <<<dim3(128, 4), 256, 0, stream>>>(images, w1t, b1, h);
    k_conv2m<<<36 * nz, 256, 0, stream>>>(h, wt, pacc, ksteps, lgci, ncg, tpz);
    k_cred  <<<4608, 256, 0, stream>>>(pacc, bp, u, nz);
    k_uhat  <<<dim3(72, 10), 256, 0, stream>>>(u, Wdig, uh);
    k_routing<<<dim3(10, 128), 256, 0, stream>>>(uh, caps);
    k_sel   <<<128, 64, 0, stream>>>(caps, yout, fs, idxf);
    k_fc1   <<<128, 512, 0, stream>>>(fs, idxf, Wd1, bd1, h1);
    k_fc2   <<<dim3(4, 8), 256, 0, stream>>>(h1, Wd2, bd2, h2);
    k_fc3   <<<dim3(4, 16), 256, 0, stream>>>(h2, Wd3, bd3, rec);
}